// Round 1
// baseline (106.995 us; speedup 1.0000x reference)
//
#include <hip/hip_runtime.h>
#include <cstddef>

// ---- real-basis CG constants ----
// l=1: C1[a][b][c] = -eps_{abc}/sqrt(6)  (global sign cancels in gram)
// l=2: derived by hand from complex CG + e3nn real transform, norm'd to 1.
#define K_A 0.2390457218668787f    // 2/sqrt(70)
#define K_B 0.11952286093343936f   // 1/sqrt(70)
#define K_G 0.20701966780270626f   // 3/sqrt(210)

struct C2T {
    float v[5][5][5];
    constexpr C2T() : v{} {
        v[2][2][2] = -K_A;
        v[2][1][1] = -K_B; v[2][3][3] = -K_B; v[1][2][1] = -K_B;
        v[3][2][3] = -K_B; v[1][1][2] = -K_B; v[3][3][2] = -K_B;
        v[2][0][0] =  K_A; v[2][4][4] =  K_A; v[0][2][0] =  K_A;
        v[4][2][4] =  K_A; v[0][0][2] =  K_A; v[4][4][2] =  K_A;
        v[1][1][4] =  K_G; v[4][1][1] =  K_G; v[1][4][1] =  K_G;
        v[3][3][4] = -K_G; v[4][3][3] = -K_G; v[3][4][3] = -K_G;
        v[1][3][0] = -K_G; v[3][1][0] = -K_G; v[0][1][3] = -K_G;
        v[0][3][1] = -K_G; v[1][0][3] = -K_G; v[3][0][1] = -K_G;
    }
};
constexpr C2T C2c{};

__global__ __launch_bounds__(256) void zero_kernel(float* __restrict__ out, int n) {
    int i = blockIdx.x * blockDim.x + threadIdx.x;
    if (i < n) out[i] = 0.0f;
}

__global__ __launch_bounds__(256) void atom_kernel(
    const float* __restrict__ Hs, const float* __restrict__ Hp,
    const float* __restrict__ Hd, const int* __restrict__ gid,
    const float* __restrict__ wsp, const float* __restrict__ wpp,
    const float* __restrict__ wdp, float* __restrict__ out, int N)
{
    int n = blockIdx.x * blockDim.x + threadIdx.x;
    if (n >= N) return;
    const float ws = wsp[0], wp = wpp[0], wd = wdp[0];

    // ---- s channel: ts = ws^4 * prod(H_s); feat = ts^2/16
    const float4 hs = *(const float4*)(Hs + (size_t)n * 4);
    const float ws2 = ws * ws;
    const float ts = (ws2 * ws2) * hs.x * hs.y * hs.z * hs.w;
    float total = ts * ts * (1.0f / 16.0f);

    // ---- p channel: 3 sequential scaled cross products per row, gram-sum
    {
        const float* hp = Hp + (size_t)n * 27;
        const float cp = -wp * 0.70710678118654752f;  // -wp*sqrt(3)/sqrt(6)
        float t[3][3] = {{1,0,0},{0,1,0},{0,0,1}};
        #pragma unroll
        for (int s = 0; s < 3; s++) {
            #pragma unroll
            for (int b = 0; b < 3; b++) {
                const float h0 = hp[s*9 + b*3 + 0];
                const float h1 = hp[s*9 + b*3 + 1];
                const float h2 = hp[s*9 + b*3 + 2];
                const float c0 = t[b][1]*h2 - t[b][2]*h1;
                const float c1 = t[b][2]*h0 - t[b][0]*h2;
                const float c2 = t[b][0]*h1 - t[b][1]*h0;
                t[b][0] = cp * c0; t[b][1] = cp * c1; t[b][2] = cp * c2;
            }
        }
        const float u0 = t[0][0] + t[1][0] + t[2][0];
        const float u1 = t[0][1] + t[1][1] + t[2][1];
        const float u2 = t[0][2] + t[1][2] + t[2][2];
        total += (u0*u0 + u1*u1 + u2*u2) * (1.0f / 9.0f);
    }

    // ---- d channel: two CG contractions (eye -> t1 -> t2), gram-sum
    {
        const float* hd = Hd + (size_t)n * 50;
        const float sd = wd * 2.23606797749978969f;   // wd*sqrt(5)
        float u[5] = {0, 0, 0, 0, 0};
        #pragma unroll
        for (int b = 0; b < 5; b++) {
            float h0r[5], h1r[5], t1r[5];
            #pragma unroll
            for (int j = 0; j < 5; j++) h0r[j] = hd[b*5 + j];
            #pragma unroll
            for (int k = 0; k < 5; k++) {
                float acc = 0.0f;
                #pragma unroll
                for (int j = 0; j < 5; j++) acc += C2c.v[b][j][k] * h0r[j];
                t1r[k] = sd * acc;
            }
            #pragma unroll
            for (int j = 0; j < 5; j++) h1r[j] = hd[25 + b*5 + j];
            #pragma unroll
            for (int k = 0; k < 5; k++) {
                float acc = 0.0f;
                #pragma unroll
                for (int i = 0; i < 5; i++)
                    #pragma unroll
                    for (int j = 0; j < 5; j++)
                        acc += C2c.v[i][j][k] * (t1r[i] * h1r[j]);
                u[k] += sd * acc;
            }
        }
        total += (u[0]*u[0] + u[1]*u[1] + u[2]*u[2] + u[3]*u[3] + u[4]*u[4]) * 0.25f;
    }

    unsafeAtomicAdd(out + gid[n], total);
}

__global__ __launch_bounds__(256) void edge_kernel(
    const float* __restrict__ pos, const int* __restrict__ src,
    const int* __restrict__ dst, float* __restrict__ emb, int E)
{
    int e = blockIdx.x * blockDim.x + threadIdx.x;
    if (e >= E) return;
    const int s = src[e], d = dst[e];
    const float dx = pos[d*3 + 0] - pos[s*3 + 0];
    const float dy = pos[d*3 + 1] - pos[s*3 + 1];
    const float dz = pos[d*3 + 2] - pos[s*3 + 2];
    const float r = sqrtf(dx*dx + dy*dy + dz*dz + 1e-12f);
    const float rs = r * 2.2f;  // r/step, step = 5/11

    float o[10];
    #pragma unroll
    for (int q = 0; q < 10; q++) {
        const float dd = rs - (float)(q + 1);
        const float d2 = dd * dd;
        const bool inside = d2 < 1.0f;
        const float denom = inside ? (1.0f - d2) : 1.0f;
        const float b = (1.14136f * expf(2.0f - 2.0f / denom)) * 3.16227766016838f;
        o[q] = inside ? b : 0.0f;
    }

    float2* p2 = (float2*)(emb + (size_t)e * 10);
    p2[0] = make_float2(o[0], o[1]);
    p2[1] = make_float2(o[2], o[3]);
    p2[2] = make_float2(o[4], o[5]);
    p2[3] = make_float2(o[6], o[7]);
    p2[4] = make_float2(o[8], o[9]);
}

extern "C" void kernel_launch(void* const* d_in, const int* in_sizes, int n_in,
                              void* d_out, int out_size, void* d_ws, size_t ws_size,
                              hipStream_t stream) {
    const float* Hs  = (const float*)d_in[0];
    const float* Hp  = (const float*)d_in[1];
    const float* Hd  = (const float*)d_in[2];
    const float* pos = (const float*)d_in[3];
    const float* wsp = (const float*)d_in[4];
    const float* wpp = (const float*)d_in[5];
    const float* wdp = (const float*)d_in[6];
    const int* esrc  = (const int*)d_in[7];
    const int* edst  = (const int*)d_in[8];
    const int* gid   = (const int*)d_in[9];

    const int N = in_sizes[0] / 4;
    const int E = in_sizes[7];
    const int G = out_size - 10 * E;   // 2000

    float* out = (float*)d_out;
    float* emb = out + G;

    zero_kernel<<<(G + 255) / 256, 256, 0, stream>>>(out, G);
    atom_kernel<<<(N + 255) / 256, 256, 0, stream>>>(Hs, Hp, Hd, gid, wsp, wpp, wdp, out, N);
    edge_kernel<<<(E + 255) / 256, 256, 0, stream>>>(pos, esrc, edst, emb, E);
}